// Round 1
// baseline (81.803 us; speedup 1.0000x reference)
//
#include <hip/hip_runtime.h>
#include <hip/hip_bf16.h>

#define T_LEN 2048
#define NCOMP 8
#define HID 64
#define OUT_DIM 64
#define BATCH 64
#define MAX_EVENTS (T_LEN * NCOMP)

// ---------------------------------------------------------------------------
// Kernel 1: per (b, c) channel — run-length encode + accumulate relu(a_e)
// into a 64-dim partial sum + event count.
// a_e = W1[c] + b1 + s*W1[8] + (t/(T-1))*W1[9] + (dur/T)*W1[10]
// ---------------------------------------------------------------------------
__global__ __launch_bounds__(256) void rle_accum_kernel(
    const float* __restrict__ x,   // [B, T, C]
    const float* __restrict__ W1,  // [11, 64] row-major
    const float* __restrict__ b1,  // [64]
    float* __restrict__ ws)        // [512][65]: 64 sums + count
{
    const int bc = blockIdx.x;          // 0..511
    const int b  = bc >> 3;
    const int c  = bc & 7;
    const int tid = threadIdx.x;

    __shared__ int bits[T_LEN];
    __shared__ int ns[T_LEN];           // next-start (suffix min of shifted sp)
    __shared__ float Sp[4][HID];
    __shared__ int cnt_sh;

    if (tid == 0) cnt_sh = 0;

    // --- load + binarize channel ---
    const float* xp = x + ((size_t)b * T_LEN) * NCOMP + c;
    #pragma unroll
    for (int i = 0; i < 8; ++i) {
        int t = tid + i * 256;
        bits[t] = (xp[(size_t)t * NCOMP] > 0.5f) ? 1 : 0;
    }
    __syncthreads();

    // --- is_start + init shifted start-pos array: ns[t] = sp[t+1], ns[T-1]=T ---
    int localCount = 0;
    #pragma unroll
    for (int i = 0; i < 8; ++i) {
        int t = tid + i * 256;
        int bt = bits[t];
        int tm = (t > 0) ? (t - 1) : 0;
        int st = (t == 0) ? 1 : (bits[tm] != bt);
        localCount += st;
        int sp = st ? t : T_LEN;
        if (t >= 1) ns[t - 1] = sp;
        if (t == T_LEN - 1) ns[T_LEN - 1] = T_LEN;
    }
    atomicAdd(&cnt_sh, localCount);
    __syncthreads();

    // --- suffix min scan: ns[t] = min_{t'>t} sp[t'] ---
    for (int off = 1; off < T_LEN; off <<= 1) {
        int v[8];
        #pragma unroll
        for (int i = 0; i < 8; ++i) {
            int t = tid + i * 256;
            v[i] = (t + off < T_LEN) ? ns[t + off] : T_LEN;
        }
        __syncthreads();
        #pragma unroll
        for (int i = 0; i < 8; ++i) {
            int t = tid + i * 256;
            if (v[i] < ns[t]) ns[t] = v[i];
        }
        __syncthreads();
    }

    // --- accumulate relu activations over start slots ---
    const int g = tid >> 6;   // event group 0..3
    const int h = tid & 63;   // hid dim
    const float base = W1[c * HID + h] + b1[h];
    const float r8  = W1[8 * HID + h];
    const float r9  = W1[9 * HID + h];
    const float r10 = W1[10 * HID + h];

    float S = 0.0f;
    for (int t = g; t < T_LEN; t += 4) {
        int bt = bits[t];
        int tm = (t > 0) ? (t - 1) : 0;
        bool st = (t == 0) || (bits[tm] != bt);
        if (st) {  // wave-uniform branch: all 64 lanes share t
            float dur = (float)(ns[t] - t);
            float a = fmaf((float)bt, r8, base);
            a = fmaf((float)t * (1.0f / 2047.0f), r9, a);
            a = fmaf(dur * (1.0f / 2048.0f), r10, a);
            S += fmaxf(a, 0.0f);
        }
    }
    Sp[g][h] = S;
    __syncthreads();

    if (tid < HID) {
        float s = Sp[0][tid] + Sp[1][tid] + Sp[2][tid] + Sp[3][tid];
        ws[(size_t)bc * 65 + tid] = s;
    }
    if (tid == HID) {
        ws[(size_t)bc * 65 + 64] = (float)cnt_sh;
    }
}

// ---------------------------------------------------------------------------
// Kernel 2: per batch — pooled = (S @ W2)/valid + b2; z = [pooled, valid/16384]
// out = relu(z @ P1 + pb1) @ P2 + pb2
// ---------------------------------------------------------------------------
__global__ __launch_bounds__(64) void head_kernel(
    const float* __restrict__ ws,   // [512][65]
    const float* __restrict__ W2,   // [64, 64]
    const float* __restrict__ b2,   // [64]
    const float* __restrict__ P1,   // [65, 64]
    const float* __restrict__ pb1,  // [64]
    const float* __restrict__ P2,   // [64, 64]
    const float* __restrict__ pb2,  // [64]
    float* __restrict__ out)        // [64, 64]
{
    const int b = blockIdx.x;
    const int h = threadIdx.x;

    __shared__ float sb[HID];
    __shared__ float z[HID + 1];
    __shared__ float y[HID];

    float s = 0.0f, cnt = 0.0f;
    #pragma unroll
    for (int c = 0; c < NCOMP; ++c) {
        s   += ws[(size_t)(b * NCOMP + c) * 65 + h];
        cnt += ws[(size_t)(b * NCOMP + c) * 65 + 64];
    }
    float valid = fmaxf(cnt, 1.0f);
    sb[h] = s;
    __syncthreads();

    float acc = 0.0f;
    #pragma unroll
    for (int k = 0; k < HID; ++k) acc = fmaf(sb[k], W2[k * HID + h], acc);
    z[h] = acc / valid + b2[h];
    if (h == 0) z[HID] = valid / (float)MAX_EVENTS;
    __syncthreads();

    float a1 = pb1[h];
    #pragma unroll
    for (int k = 0; k < HID + 1; ++k) a1 = fmaf(z[k], P1[k * HID + h], a1);
    y[h] = fmaxf(a1, 0.0f);
    __syncthreads();

    float o = pb2[h];
    #pragma unroll
    for (int k = 0; k < HID; ++k) o = fmaf(y[k], P2[k * HID + h], o);
    out[(size_t)b * OUT_DIM + h] = o;
}

extern "C" void kernel_launch(void* const* d_in, const int* in_sizes, int n_in,
                              void* d_out, int out_size, void* d_ws, size_t ws_size,
                              hipStream_t stream) {
    const float* x   = (const float*)d_in[0];
    const float* W1  = (const float*)d_in[1];
    const float* b1  = (const float*)d_in[2];
    const float* W2  = (const float*)d_in[3];
    const float* b2  = (const float*)d_in[4];
    const float* P1  = (const float*)d_in[5];
    const float* pb1 = (const float*)d_in[6];
    const float* P2  = (const float*)d_in[7];
    const float* pb2 = (const float*)d_in[8];
    float* out = (float*)d_out;
    float* ws  = (float*)d_ws;   // needs 512*65*4 = 133,120 bytes

    rle_accum_kernel<<<BATCH * NCOMP, 256, 0, stream>>>(x, W1, b1, ws);
    head_kernel<<<BATCH, 64, 0, stream>>>(ws, W2, b2, P1, pb1, P2, pb2, out);
}

// Round 2
// 30.579 us; speedup vs baseline: 2.6751x; 2.6751x over previous
//
#include <hip/hip_runtime.h>
#include <hip/hip_bf16.h>

#define T_LEN 2048
#define NCOMP 8
#define HID 64
#define OUT_DIM 64
#define BATCH 64
#define MAX_EVENTS (T_LEN * NCOMP)
#define NCHUNK 32              // 2048 / 64 bit-chunks per channel
#define SEGB 16                // event-blocks per batch: 8 channels * 2 halves
#define PART_STRIDE 66         // 64 sums + count + pad

// ws layout:
//   [0, 131072)                 : unsigned long long words[64][8][32]
//   [131072, 131072+64*16*66*4) : float partial[64][16][66]
#define WORDS_BYTES (64ULL * 8 * 32 * 8)

// ---------------------------------------------------------------------------
// Kernel A: coalesced binarize + bit-pack. Block = (b, seg of 256 t).
// ---------------------------------------------------------------------------
__global__ __launch_bounds__(256) void pack_kernel(
    const float* __restrict__ x,         // [B, T, C]
    unsigned long long* __restrict__ words)  // [64][8][32]
{
    const int b   = blockIdx.x >> 3;
    const int seg = blockIdx.x & 7;
    const int tid = threadIdx.x;
    const int t   = seg * 256 + tid;

    const float4* xp = (const float4*)(x + ((size_t)b * T_LEN + t) * NCOMP);
    float4 v0 = xp[0];
    float4 v1 = xp[1];

    unsigned int m = 0;
    m |= (v0.x > 0.5f) ? 1u : 0u;
    m |= (v0.y > 0.5f) ? 2u : 0u;
    m |= (v0.z > 0.5f) ? 4u : 0u;
    m |= (v0.w > 0.5f) ? 8u : 0u;
    m |= (v1.x > 0.5f) ? 16u : 0u;
    m |= (v1.y > 0.5f) ? 32u : 0u;
    m |= (v1.z > 0.5f) ? 64u : 0u;
    m |= (v1.w > 0.5f) ? 128u : 0u;

    const int lane  = tid & 63;
    const int wave  = tid >> 6;
    const int chunk = seg * 4 + wave;    // 0..31

    unsigned long long mine = 0;
    #pragma unroll
    for (int c = 0; c < NCOMP; ++c) {
        unsigned long long wd = __ballot((m >> c) & 1u);
        if (lane == c) mine = wd;
    }
    if (lane < NCOMP) {
        words[((size_t)b * NCOMP + lane) * NCHUNK + chunk] = mine;
    }
}

// ---------------------------------------------------------------------------
// Kernel B: per (b, c, half): build compact event list, accumulate
// S[h] = sum over events of relu(base + s*r8 + tn*r9 + dn*r10).
// ---------------------------------------------------------------------------
__global__ __launch_bounds__(256) void event_kernel(
    const unsigned long long* __restrict__ words,  // [64][8][32]
    const float* __restrict__ W1,   // [11, 64]
    const float* __restrict__ b1,   // [64]
    float* __restrict__ partial)    // [64][16][66]
{
    const int blk  = blockIdx.x;
    const int b    = blk >> 4;
    const int rem  = blk & 15;
    const int c    = rem >> 1;
    const int half = rem & 1;
    const int t0   = half * 1024;
    const int tid  = threadIdx.x;
    const int lane = tid & 63;
    const int wave = tid >> 6;

    __shared__ unsigned long long wsh[NCHUNK];   // raw bits
    __shared__ unsigned long long tsh[NCHUNK];   // transition (start) masks
    __shared__ unsigned int elist[1024];
    __shared__ int wtot[4];
    __shared__ float Sp[4][HID];

    if (tid < NCHUNK) {
        wsh[tid] = words[((size_t)b * NCOMP + c) * NCHUNK + tid];
    }
    __syncthreads();
    if (tid < NCHUNK) {
        unsigned long long w = wsh[tid];
        unsigned long long carry = (tid > 0) ? (wsh[tid - 1] >> 63) : 0ULL;
        unsigned long long tr = w ^ ((w << 1) | carry);
        if (tid == 0) tr |= 1ULL;    // t=0 always a start
        tsh[tid] = tr;
    }
    __syncthreads();

    // --- per-thread: 4 consecutive t positions ---
    unsigned int evt[4];
    int nt = 0;
    const int tbase = t0 + tid * 4;
    #pragma unroll
    for (int k = 0; k < 4; ++k) {
        int t   = tbase + k;
        int ch  = t >> 6;
        int pos = t & 63;
        unsigned long long tr = tsh[ch];
        if ((tr >> pos) & 1ULL) {
            int s = (int)((wsh[ch] >> pos) & 1ULL);
            // next transition strictly after t
            unsigned long long rem64 = (pos == 63) ? 0ULL : (tr & (~0ULL << (pos + 1)));
            int nxt;
            if (rem64) {
                nxt = ch * 64 + (__ffsll(rem64) - 1);
            } else {
                int c2 = ch + 1;
                while (c2 < NCHUNK && tsh[c2] == 0ULL) ++c2;
                nxt = (c2 < NCHUNK) ? c2 * 64 + (__ffsll(tsh[c2]) - 1) : T_LEN;
            }
            int dur = nxt - t;
            evt[nt++] = (unsigned int)t | ((unsigned int)dur << 11) | ((unsigned int)s << 23);
        }
    }

    // --- deterministic compaction: shfl prefix sum within wave + wave offsets ---
    int incl = nt;
    #pragma unroll
    for (int o = 1; o < 64; o <<= 1) {
        int v = __shfl_up(incl, o);
        if (lane >= o) incl += v;
    }
    if (lane == 63) wtot[wave] = incl;
    __syncthreads();
    int waveoff = 0;
    for (int w = 0; w < wave; ++w) waveoff += wtot[w];
    int nE = wtot[0] + wtot[1] + wtot[2] + wtot[3];
    int off = waveoff + incl - nt;
    for (int k = 0; k < nt; ++k) elist[off + k] = evt[k];
    __syncthreads();

    // --- accumulate over compact events; dims across lanes, events across groups ---
    const int g = wave;
    const int h = lane;
    const float base = W1[c * HID + h] + b1[h];
    const float r8   = W1[8 * HID + h];
    const float r9   = W1[9 * HID + h];
    const float r10  = W1[10 * HID + h];
    const float inv2047 = 1.0f / 2047.0f;
    const float inv2048 = 1.0f / 2048.0f;

    float S = 0.0f;
    for (int i = g; i < nE; i += 4) {
        unsigned int e = elist[i];
        float pos = (float)(e & 2047u);
        float dur = (float)((e >> 11) & 4095u);
        float s   = (float)(e >> 23);
        float a = fmaf(s, r8, base);
        a = fmaf(pos * inv2047, r9, a);
        a = fmaf(dur * inv2048, r10, a);
        S += fmaxf(a, 0.0f);
    }
    Sp[g][h] = S;
    __syncthreads();

    float* pp = partial + ((size_t)b * SEGB + rem) * PART_STRIDE;
    if (tid < HID) {
        pp[tid] = Sp[0][tid] + Sp[1][tid] + Sp[2][tid] + Sp[3][tid];
    }
    if (tid == HID) {
        pp[HID] = (float)nE;
    }
}

// ---------------------------------------------------------------------------
// Kernel C: head. pooled = (S @ W2)/valid + b2; z = [pooled, valid/16384];
// out = relu(z @ P1 + pb1) @ P2 + pb2
// ---------------------------------------------------------------------------
__global__ __launch_bounds__(64) void head_kernel(
    const float* __restrict__ partial,  // [64][16][66]
    const float* __restrict__ W2,
    const float* __restrict__ b2,
    const float* __restrict__ P1,
    const float* __restrict__ pb1,
    const float* __restrict__ P2,
    const float* __restrict__ pb2,
    float* __restrict__ out)
{
    const int b = blockIdx.x;
    const int h = threadIdx.x;

    __shared__ float sb[HID];
    __shared__ float z[HID + 1];
    __shared__ float y[HID];

    float s = 0.0f, cnt = 0.0f;
    #pragma unroll
    for (int j = 0; j < SEGB; ++j) {
        const float* pp = partial + ((size_t)b * SEGB + j) * PART_STRIDE;
        s   += pp[h];
        cnt += pp[HID];
    }
    float valid = fmaxf(cnt, 1.0f);
    sb[h] = s;
    __syncthreads();

    float acc = 0.0f;
    #pragma unroll
    for (int k = 0; k < HID; ++k) acc = fmaf(sb[k], W2[k * HID + h], acc);
    z[h] = acc / valid + b2[h];
    if (h == 0) z[HID] = valid / (float)MAX_EVENTS;
    __syncthreads();

    float a1 = pb1[h];
    #pragma unroll
    for (int k = 0; k < HID + 1; ++k) a1 = fmaf(z[k], P1[k * HID + h], a1);
    y[h] = fmaxf(a1, 0.0f);
    __syncthreads();

    float o = pb2[h];
    #pragma unroll
    for (int k = 0; k < HID; ++k) o = fmaf(y[k], P2[k * HID + h], o);
    out[(size_t)b * OUT_DIM + h] = o;
}

extern "C" void kernel_launch(void* const* d_in, const int* in_sizes, int n_in,
                              void* d_out, int out_size, void* d_ws, size_t ws_size,
                              hipStream_t stream) {
    const float* x   = (const float*)d_in[0];
    const float* W1  = (const float*)d_in[1];
    const float* b1  = (const float*)d_in[2];
    const float* W2  = (const float*)d_in[3];
    const float* b2  = (const float*)d_in[4];
    const float* P1  = (const float*)d_in[5];
    const float* pb1 = (const float*)d_in[6];
    const float* P2  = (const float*)d_in[7];
    const float* pb2 = (const float*)d_in[8];
    float* out = (float*)d_out;

    unsigned long long* words = (unsigned long long*)d_ws;
    float* partial = (float*)((char*)d_ws + WORDS_BYTES);
    // ws needed: 131072 + 64*16*66*4 = 401,408 bytes

    pack_kernel<<<BATCH * 8, 256, 0, stream>>>(x, words);
    event_kernel<<<BATCH * SEGB, 256, 0, stream>>>(words, W1, b1, partial);
    head_kernel<<<BATCH, 64, 0, stream>>>(partial, W2, b2, P1, pb1, P2, pb2, out);
}